// Round 4
// baseline (533.348 us; speedup 1.0000x reference)
//
#include <hip/hip_runtime.h>
#include <hip/hip_bf16.h>
#include <hip/hip_fp16.h>

#define N_NODES 10000
#define N_PAIRS 200000
#define NFEAT 384
#define FH 128
#define SPH 15

typedef __bf16 bf16x8 __attribute__((ext_vector_type(8)));
typedef _Float16 half8 __attribute__((ext_vector_type(8)));
typedef float f32x4 __attribute__((ext_vector_type(4)));

// ---------------- q/k GEMM ----------------
// q[n, h*128+g] = sum_f x[n, h*128+f] * Wq[h, g, f]   (and same for k)
// MFMA 16x16x32 bf16, outputs stored fp16 (halves gather traffic downstream).
__device__ inline bf16x8 cvt8(const float* __restrict__ p) {
    float4 lo = *(const float4*)p;
    float4 hi = *(const float4*)(p + 4);
    bf16x8 r;
    r[0] = (__bf16)lo.x; r[1] = (__bf16)lo.y; r[2] = (__bf16)lo.z; r[3] = (__bf16)lo.w;
    r[4] = (__bf16)hi.x; r[5] = (__bf16)hi.y; r[6] = (__bf16)hi.z; r[7] = (__bf16)hi.w;
    return r;
}

__global__ __launch_bounds__(256) void qk_gemm_kernel(
        const float* __restrict__ x,
        const float* __restrict__ Wq,
        const float* __restrict__ Wk,
        _Float16* __restrict__ q, _Float16* __restrict__ k) {
    const int head = blockIdx.y;
    const int node0 = blockIdx.x * 16;
    const int wave = threadIdx.x >> 6;
    const int lane = threadIdx.x & 63;
    const int mrow = lane & 15;
    const int quad = lane >> 4;
    const float* xrow = x + (size_t)(node0 + mrow) * NFEAT + head * FH + quad * 8;
    bf16x8 afrag[4];
#pragma unroll
    for (int t = 0; t < 4; ++t) afrag[t] = cvt8(xrow + t * 32);

    for (int task = wave; task < 16; task += 4) {
        const int mat = task & 1;
        const int g0 = (task >> 1) * 16;
        const float* Wrow =
            (mat ? Wk : Wq) + (size_t)head * FH * FH + (size_t)(g0 + mrow) * FH + quad * 8;
        f32x4 acc = {0.f, 0.f, 0.f, 0.f};
#pragma unroll
        for (int t = 0; t < 4; ++t) {
            bf16x8 b = cvt8(Wrow + t * 32);
            acc = __builtin_amdgcn_mfma_f32_16x16x32_bf16(afrag[t], b, acc, 0, 0, 0);
        }
        _Float16* dst = mat ? k : q;
        const int g = g0 + mrow;
#pragma unroll
        for (int r = 0; r < 4; ++r) {
            const int node = node0 + quad * 4 + r;
            dst[(size_t)node * NFEAT + head * FH + g] = (_Float16)acc[r];
        }
    }
}

// ---------------- pair phase: 8 lanes/pair, 8 pairs/wave ----------------
// 8-lane-group sum, all on the VALU/DPP pipe:
//   half_mirror (l^7 within 8) -> quad_perm l^3 -> quad_perm l^1
template <int CTRL>
__device__ __forceinline__ float dpp_add(float v) {
    int r = __builtin_amdgcn_update_dpp(0, __builtin_bit_cast(int, v), CTRL,
                                        0xf, 0xf, true);
    return v + __builtin_bit_cast(float, r);
}
__device__ __forceinline__ float grp8_sum(float v) {
    v = dpp_add<0x141>(v);  // row_half_mirror: partner = l ^ 7 (within 8)
    v = dpp_add<0x1B>(v);   // quad_perm [3,2,1,0]: partner = l ^ 3
    v = dpp_add<0xB1>(v);   // quad_perm [1,0,3,2]: partner = l ^ 1
    return v;
}

// Lane `sl` (0..7) owns 16 feats/head. 8 pairs in flight per wave iteration
// (2x the MLP of the 16-lane version, half the loop/reduce overhead).
// N_PAIRS % 8 == 0 and the grid stride is a multiple of 8, so no tail guard.
// alpha[h] = (sum_f q[i,h,f]*w[e,h,f]*k[j,h,f]) / sqrt(128) * (phi_r[e]+phi_chi[e])
// Each lane then scatters components c=sl and c=sl+8 (c<15) of alpha_rep*sph.
__global__ __launch_bounds__(256) void pair_kernel(
        const _Float16* __restrict__ q, const _Float16* __restrict__ kk,
        const float* __restrict__ w_ij, const float* __restrict__ sph,
        const int* __restrict__ idx_i, const int* __restrict__ idx_j,
        const float* __restrict__ phi_r, const float* __restrict__ phi_chi,
        float* __restrict__ out) {
    const int lane = threadIdx.x & 63;
    const int sl = lane & 7;     // lane within pair-group
    const int grp = lane >> 3;   // which of 8 pairs in this wave
    const int wid = blockIdx.x * (blockDim.x >> 6) + (threadIdx.x >> 6);
    const int nw = gridDim.x * (blockDim.x >> 6);
    for (int base = wid * 8; base < N_PAIRS; base += nw * 8) {
        const int e = base + grp;  // always < N_PAIRS
        const int i = __builtin_nontemporal_load(idx_i + e);
        const int j = __builtin_nontemporal_load(idx_j + e);
        const float pr = __builtin_nontemporal_load(phi_r + e);
        const float pc = __builtin_nontemporal_load(phi_chi + e);
        const float s1 = __builtin_nontemporal_load(sph + (size_t)e * SPH + sl);
        const float s2 = (sl < 7)
            ? __builtin_nontemporal_load(sph + (size_t)e * SPH + sl + 8) : 0.f;
        const _Float16* qr = q + (size_t)i * NFEAT;
        const _Float16* kr = kk + (size_t)j * NFEAT;
        const float* wr = w_ij + (size_t)e * NFEAT;
        float dot[3];
#pragma unroll
        for (int h = 0; h < 3; ++h) {
            const int f = h * FH + sl * 16;
            half8 qa = *(const half8*)(qr + f);
            half8 qb = *(const half8*)(qr + f + 8);
            half8 ka = *(const half8*)(kr + f);
            half8 kb = *(const half8*)(kr + f + 8);
            f32x4 w0 = __builtin_nontemporal_load((const f32x4*)(wr + f));
            f32x4 w1 = __builtin_nontemporal_load((const f32x4*)(wr + f + 4));
            f32x4 w2 = __builtin_nontemporal_load((const f32x4*)(wr + f + 8));
            f32x4 w3 = __builtin_nontemporal_load((const f32x4*)(wr + f + 12));
            float d = 0.f;
#pragma unroll
            for (int u = 0; u < 4; ++u) {
                d = fmaf((float)qa[u] * w0[u], (float)ka[u], d);
                d = fmaf((float)qa[u + 4] * w1[u], (float)ka[u + 4], d);
                d = fmaf((float)qb[u] * w2[u], (float)kb[u], d);
                d = fmaf((float)qb[u + 4] * w3[u], (float)kb[u + 4], d);
            }
            dot[h] = grp8_sum(d);
        }
        const float scale = (pr + pc) * 0.088388347648318447f;  // 1/sqrt(128)
        // c1 = sl (heads 0/1), c2 = sl + 8 (head 2; sl==7 -> c2==15, skipped)
        const float v1 = dot[(sl < 3) ? 0 : 1] * scale * s1;
        unsafeAtomicAdd(&out[(size_t)i * SPH + sl], v1);
        if (sl < 7) {
            const float v2 = dot[2] * scale * s2;
            unsafeAtomicAdd(&out[(size_t)i * SPH + sl + 8], v2);
        }
    }
}

extern "C" void kernel_launch(void* const* d_in, const int* in_sizes, int n_in,
                              void* d_out, int out_size, void* d_ws, size_t ws_size,
                              hipStream_t stream) {
    // inputs: 0 chi (unused), 1 sph_ij, 2 x, 3 w_ij, 4 idx_i, 5 phi_r_cut,
    //         6 phi_chi_cut, 7 idx_j, 8 Wq, 9 Wk
    const float* sph     = (const float*)d_in[1];
    const float* x       = (const float*)d_in[2];
    const float* w_ij    = (const float*)d_in[3];
    const int*   idx_i   = (const int*)d_in[4];
    const float* phi_r   = (const float*)d_in[5];
    const float* phi_chi = (const float*)d_in[6];
    const int*   idx_j   = (const int*)d_in[7];
    const float* Wq      = (const float*)d_in[8];
    const float* Wk      = (const float*)d_in[9];
    float* out = (float*)d_out;

    // workspace layout: q (7.68 MB fp16) + k (7.68 MB fp16)
    char* ws = (char*)d_ws;
    _Float16* qws = (_Float16*)ws;
    _Float16* kws = (_Float16*)(ws + 7680000);

    hipMemsetAsync(d_out, 0, (size_t)out_size * sizeof(float), stream);

    qk_gemm_kernel<<<dim3(N_NODES / 16, 3), 256, 0, stream>>>(x, Wq, Wk, qws, kws);

    pair_kernel<<<2048, 256, 0, stream>>>(qws, kws, w_ij, sph, idx_i, idx_j,
                                          phi_r, phi_chi, out);
}

// Round 5
// 469.647 us; speedup vs baseline: 1.1356x; 1.1356x over previous
//
#include <hip/hip_runtime.h>
#include <hip/hip_bf16.h>
#include <hip/hip_fp16.h>

#define N_NODES 10000
#define N_PAIRS 200000
#define NFEAT 384
#define FH 128
#define SPH 15

typedef __bf16 bf16x8 __attribute__((ext_vector_type(8)));
typedef __bf16 bf16x4 __attribute__((ext_vector_type(4)));
typedef _Float16 half8 __attribute__((ext_vector_type(8)));
typedef float f32x4 __attribute__((ext_vector_type(4)));

// ---------------- one-shot f32 -> bf16 pre-conversion ----------------
// x (3.84M), Wq (49152), Wk (49152). RNE cast == the old per-block cvt8,
// so numerics are bit-identical; removes 625x-redundant W conversion from
// the GEMM and halves its W bytes.
__global__ __launch_bounds__(256) void cvt_kernel(
        const float* __restrict__ x, const float* __restrict__ Wq,
        const float* __restrict__ Wk, __bf16* __restrict__ xb,
        __bf16* __restrict__ wqb, __bf16* __restrict__ wkb) {
    const int XN4 = (N_NODES * NFEAT) / 4;   // 960000
    const int WN4 = (3 * FH * FH) / 4;       // 12288
    const int total = XN4 + 2 * WN4;
    for (int t = blockIdx.x * blockDim.x + threadIdx.x; t < total;
         t += gridDim.x * blockDim.x) {
        const float* src;
        __bf16* dst;
        int o;
        if (t < XN4)            { src = x;  dst = xb;  o = t; }
        else if (t < XN4 + WN4) { src = Wq; dst = wqb; o = t - XN4; }
        else                    { src = Wk; dst = wkb; o = t - XN4 - WN4; }
        float4 v = *(const float4*)(src + (size_t)o * 4);
        bf16x4 r;
        r[0] = (__bf16)v.x; r[1] = (__bf16)v.y;
        r[2] = (__bf16)v.z; r[3] = (__bf16)v.w;
        *(bf16x4*)(dst + (size_t)o * 4) = r;
    }
}

// ---------------- q/k GEMM (bf16 in, fp16 out) ----------------
// q[n, h*128+g] = sum_f x[n, h*128+f] * Wq[h, g, f]   (and same for k)
// One block = 16 nodes x 1 head; 4 waves x 4 tasks (task = g-tile x q|k).
// Inner loop is now pure 16-B loads + MFMA (no VALU cvt).
// MFMA 16x16x32 bf16: A[m=lane&15][k=quad*8+j], B[k=quad*8+j][n=lane&15],
// D: col=lane&15, row=quad*4+reg  (verified gfx950 mapping).
__global__ __launch_bounds__(256) void qk_gemm_kernel(
        const __bf16* __restrict__ xb,
        const __bf16* __restrict__ Wqb,
        const __bf16* __restrict__ Wkb,
        _Float16* __restrict__ q, _Float16* __restrict__ k) {
    const int head = blockIdx.y;
    const int node0 = blockIdx.x * 16;
    const int wave = threadIdx.x >> 6;
    const int lane = threadIdx.x & 63;
    const int mrow = lane & 15;
    const int quad = lane >> 4;
    const __bf16* xrow = xb + (size_t)(node0 + mrow) * NFEAT + head * FH + quad * 8;
    bf16x8 afrag[4];
#pragma unroll
    for (int t = 0; t < 4; ++t) afrag[t] = *(const bf16x8*)(xrow + t * 32);

    for (int task = wave; task < 16; task += 4) {
        const int mat = task & 1;
        const int g0 = (task >> 1) * 16;
        const __bf16* Wrow =
            (mat ? Wkb : Wqb) + (size_t)head * FH * FH + (size_t)(g0 + mrow) * FH + quad * 8;
        f32x4 acc = {0.f, 0.f, 0.f, 0.f};
#pragma unroll
        for (int t = 0; t < 4; ++t) {
            bf16x8 b = *(const bf16x8*)(Wrow + t * 32);
            acc = __builtin_amdgcn_mfma_f32_16x16x32_bf16(afrag[t], b, acc, 0, 0, 0);
        }
        _Float16* dst = mat ? k : q;
        const int g = g0 + mrow;
#pragma unroll
        for (int r = 0; r < 4; ++r) {
            const int node = node0 + quad * 4 + r;
            dst[(size_t)node * NFEAT + head * FH + g] = (_Float16)acc[r];
        }
    }
}

// ---------------- pair phase (round-1 structure, guard-free) ----------------
// 4 pairs per wave, 16 lanes per pair. Lane `sub` owns 8 feats/head.
// alpha[h] = (sum_f q[i,h,f]*w[e,h,f]*k[j,h,f]) / sqrt(128) * (phi_r[e]+phi_chi[e])
// then subs 0..14 of each group scatter alpha_rep[c]*sph[e,c] into out[i,c].
// Grid chosen so waves*4 divides N_PAIRS exactly (3125 blocks * 4 waves * 4
// pairs * 4 iters = 200000) -> no tail guard, clean unroll.
__global__ __launch_bounds__(256) void pair_kernel(
        const _Float16* __restrict__ q, const _Float16* __restrict__ kk,
        const float* __restrict__ w_ij, const float* __restrict__ sph,
        const int* __restrict__ idx_i, const int* __restrict__ idx_j,
        const float* __restrict__ phi_r, const float* __restrict__ phi_chi,
        float* __restrict__ out) {
    const int lane = threadIdx.x & 63;
    const int sub = lane & 15;   // lane within pair-group
    const int grp = lane >> 4;   // which of 4 pairs in this wave
    const int wid = blockIdx.x * (blockDim.x >> 6) + (threadIdx.x >> 6);
    const int nw = gridDim.x * (blockDim.x >> 6);
    for (int base = wid * 4; base < N_PAIRS; base += nw * 4) {
        const int e = base + grp;  // always < N_PAIRS (grid divides exactly)
        const int i = idx_i[e];
        const int j = idx_j[e];
        const float pr = __builtin_nontemporal_load(phi_r + e);
        const float pc = __builtin_nontemporal_load(phi_chi + e);
        float sv = 0.f;
        if (sub < SPH)
            sv = __builtin_nontemporal_load(sph + (size_t)e * SPH + sub);
        const _Float16* qr = q + (size_t)i * NFEAT;
        const _Float16* kr = kk + (size_t)j * NFEAT;
        const float* wr = w_ij + (size_t)e * NFEAT;
        float dot[3];
#pragma unroll
        for (int h = 0; h < 3; ++h) {
            const int f = h * FH + sub * 8;
            half8 qv = *(const half8*)(qr + f);
            half8 kv = *(const half8*)(kr + f);
            f32x4 wa = __builtin_nontemporal_load((const f32x4*)(wr + f));
            f32x4 wb = __builtin_nontemporal_load((const f32x4*)(wr + f + 4));
            float d = 0.f;
#pragma unroll
            for (int u = 0; u < 4; ++u) {
                d = fmaf((float)qv[u] * wa[u], (float)kv[u], d);
                d = fmaf((float)qv[u + 4] * wb[u], (float)kv[u + 4], d);
            }
#pragma unroll
            for (int off = 8; off; off >>= 1) d += __shfl_xor(d, off, 16);
            dot[h] = d;
        }
        const float scale = (pr + pc) * 0.088388347648318447f;  // 1/sqrt(128)
        if (sub < SPH) {
            const int h = (sub < 3) ? 0 : (sub < 8 ? 1 : 2);
            const float val = dot[h] * scale * sv;
            unsafeAtomicAdd(&out[(size_t)i * SPH + sub], val);
        }
    }
}

extern "C" void kernel_launch(void* const* d_in, const int* in_sizes, int n_in,
                              void* d_out, int out_size, void* d_ws, size_t ws_size,
                              hipStream_t stream) {
    // inputs: 0 chi (unused), 1 sph_ij, 2 x, 3 w_ij, 4 idx_i, 5 phi_r_cut,
    //         6 phi_chi_cut, 7 idx_j, 8 Wq, 9 Wk
    const float* sph     = (const float*)d_in[1];
    const float* x       = (const float*)d_in[2];
    const float* w_ij    = (const float*)d_in[3];
    const int*   idx_i   = (const int*)d_in[4];
    const float* phi_r   = (const float*)d_in[5];
    const float* phi_chi = (const float*)d_in[6];
    const int*   idx_j   = (const int*)d_in[7];
    const float* Wq      = (const float*)d_in[8];
    const float* Wk      = (const float*)d_in[9];
    float* out = (float*)d_out;

    // workspace layout (bytes):
    //   q fp16   @ 0           (7,680,000)
    //   k fp16   @ 7,680,000   (7,680,000)
    //   x bf16   @ 15,360,000  (7,680,000)
    //   Wq bf16  @ 23,040,000  (98,304)
    //   Wk bf16  @ 23,138,304  (98,304)
    char* ws = (char*)d_ws;
    _Float16* qws = (_Float16*)ws;
    _Float16* kws = (_Float16*)(ws + 7680000);
    __bf16* xb  = (__bf16*)(ws + 15360000);
    __bf16* wqb = (__bf16*)(ws + 23040000);
    __bf16* wkb = (__bf16*)(ws + 23138304);

    hipMemsetAsync(d_out, 0, (size_t)out_size * sizeof(float), stream);

    cvt_kernel<<<2048, 256, 0, stream>>>(x, Wq, Wk, xb, wqb, wkb);

    qk_gemm_kernel<<<dim3(N_NODES / 16, 3), 256, 0, stream>>>(xb, wqb, wkb, qws, kws);

    pair_kernel<<<3125, 256, 0, stream>>>(qws, kws, w_ij, sph, idx_i, idx_j,
                                          phi_r, phi_chi, out);
}